// Round 8
// baseline (415.397 us; speedup 1.0000x reference)
//
#include <hip/hip_runtime.h>

// ---------------------------------------------------------------------------
// Model_39676907883593: out = dropout(softmax((x1 @ (m @ n^T)) / 64)) @ q
//   B=16, S=2048, D=64, DV=512.  Dropout = JAX threefry, key 42, p_keep=0.75.
// R11: SMALLER INDEPENDENT BLOCKS to break the barrier convoy:
//   - 1024 blocks x 256 thr (4 waves, 32 rows) -> 4 blocks/CU, each with its
//     own barrier domain; one block's PV MFMA covers another's QK stalls.
//   - evidence: total pipe work ~100us but R9 ran 216us with both pipes <17%
//     busy -> latency/convoy-bound, needs independent streams (TLP), not ILP.
//   - wave owns 32 keys (2 key-groups) in QK, 128 dv in PV; per-lane work and
//     total MFMA/threefry unchanged vs R7.
//   - LDS 22.5KB/block (4 res = 90KB/CU); __launch_bounds__(256,4) -> <=128
//     VGPR (phased live set ~120, no spill expected).
//   - loop semantics = R7 (verified): QK -> __syncthreads -> PV, Ps dbuf.
// ---------------------------------------------------------------------------

typedef short  s8v __attribute__((ext_vector_type(8)));
typedef float  f4v __attribute__((ext_vector_type(4)));

__device__ __forceinline__ unsigned short f2bf(float f) {
  unsigned int u = __float_as_uint(f);
  u += 0x7fffu + ((u >> 16) & 1u);           // RNE
  return (unsigned short)(u >> 16);
}
__device__ __forceinline__ float bf2f(unsigned short h) {
  return __uint_as_float(((unsigned int)h) << 16);
}

// rotl via v_alignbit: ({x,x} >> (32-r)) == rotl(x, r)
__device__ __forceinline__ unsigned int rotl(unsigned int x, unsigned int r) {
  return __builtin_amdgcn_alignbit(x, x, 32u - r);
}

// ---- threefry2x32, key = (0, 42); partitionable counter (0, idx) ----------
__device__ __forceinline__ unsigned int jax_bits(unsigned int idx) {
  const unsigned int K0 = 0u, K1 = 42u, K2 = 0x1BD11BDAu ^ K0 ^ K1;
  unsigned int x0 = 0u, x1 = idx;
  x0 += K0; x1 += K1;
#define TF_R(r) { x0 += x1; x1 = rotl(x1, r); x1 ^= x0; }
  TF_R(13) TF_R(15) TF_R(26) TF_R(6)
  x0 += K1; x1 += K2 + 1u;
  TF_R(17) TF_R(29) TF_R(16) TF_R(24)
  x0 += K2; x1 += K0 + 2u;
  TF_R(13) TF_R(15) TF_R(26) TF_R(6)
  x0 += K0; x1 += K1 + 3u;
  TF_R(17) TF_R(29) TF_R(16) TF_R(24)
  x0 += K1; x1 += K2 + 4u;
  TF_R(13) TF_R(15) TF_R(26) TF_R(6)
  x0 += K2; x1 += K0 + 5u;
#undef TF_R
  return x0 ^ x1;
}

__device__ __forceinline__ f4v mfma16(s8v a, s8v b, f4v c) {
  return __builtin_amdgcn_mfma_f32_16x16x32_bf16(a, b, c, 0, 0, 0);
}

// ---------------------------------------------------------------------------
// prep_all (unchanged, verified): build K (log2e/64 folded, hi/lo),
// cast x1 -> bf16, transpose q.
// ---------------------------------------------------------------------------
__global__ void prep_all(const float* __restrict__ x1, const float* __restrict__ q,
                         const float* __restrict__ m, const float* __restrict__ nmat,
                         unsigned short* __restrict__ Xhi, unsigned short* __restrict__ qT,
                         unsigned short* __restrict__ Khi, unsigned short* __restrict__ Klo) {
  const int blk = blockIdx.x;
  const int t = threadIdx.x;
  if (blk < 512) {                           // ---- build K ----
    __shared__ float Lm[64][68];
    const int s = blk * 4 + (t >> 6);
    const int d = t & 63;
    float a0 = 0.f, a1 = 0.f, a2 = 0.f, a3 = 0.f;
    for (int ch = 0; ch < 8; ++ch) {
      const int dv0 = ch * 64;
      __syncthreads();
#pragma unroll
      for (int k = 0; k < 4; ++k) {
        const int fi = t + k * 256;
        const int row = fi >> 4, c4 = fi & 15;
        *(float4*)&Lm[row][c4 * 4] =
            *(const float4*)&m[(size_t)row * 512 + dv0 + c4 * 4];
      }
      __syncthreads();
      const float4* nv = (const float4*)&nmat[(size_t)s * 512 + dv0];
#pragma unroll
      for (int j4 = 0; j4 < 16; ++j4) {
        const float4 nf = nv[j4];
        const float4 mf = *(const float4*)&Lm[d][j4 * 4];
        a0 = fmaf(mf.x, nf.x, a0); a1 = fmaf(mf.y, nf.y, a1);
        a2 = fmaf(mf.z, nf.z, a2); a3 = fmaf(mf.w, nf.w, a3);
      }
    }
    const float kv = ((a0 + a1) + (a2 + a3)) * (1.44269504088896340736f / 64.0f);
    const unsigned short h = f2bf(kv);
    Khi[s * 64 + d] = h;
    Klo[s * 64 + d] = f2bf(kv - bf2f(h));
  } else if (blk < 1536) {                   // ---- cast x1 -> bf16 ----
    const int i = ((blk - 512) * 256 + t) * 8;
    float4 a = *(const float4*)&x1[i];
    float4 b = *(const float4*)&x1[i + 4];
    ushort4 o0, o1;
    o0.x = f2bf(a.x); o0.y = f2bf(a.y); o0.z = f2bf(a.z); o0.w = f2bf(a.w);
    o1.x = f2bf(b.x); o1.y = f2bf(b.y); o1.z = f2bf(b.z); o1.w = f2bf(b.w);
    *(ushort4*)&Xhi[i] = o0;
    *(ushort4*)&Xhi[i + 4] = o1;
  } else {                                   // ---- transpose_q ----
    __shared__ unsigned short tile[64][65];
    const int bb = blk - 1536;
    const int s0 = (bb >> 3) * 64;
    const int d0 = (bb & 7) * 64;
#pragma unroll
    for (int k = 0; k < 16; ++k) {
      int lin = t + k * 256;
      int r = lin >> 6, c = lin & 63;
      tile[c][r] = f2bf(q[(size_t)(s0 + r) * 512 + d0 + c]);
    }
    __syncthreads();
#pragma unroll
    for (int k = 0; k < 16; ++k) {
      int lin = t + k * 256;
      int rr = lin >> 6, cc = lin & 63;
      qT[(size_t)(d0 + rr) * 2048 + s0 + cc] = tile[rr][cc];
    }
  }
}

// ---------------------------------------------------------------------------
// main fused kernel: 1024 blocks (b, rowTile32) x 256 threads (4 waves)
//   QK^T: wave w owns keys [w*32, w*32+32) (2 key-groups of 16) of the
//   128-key iter; K loaded from L2 at QK top (TLP hides latency).
//   PV: wave w owns dv slice [w*128, +128), O^T = V^T * P^T.
//   4 blocks/CU, independent barriers -> convoy broken.
// ---------------------------------------------------------------------------
__global__ __launch_bounds__(256, 4) void attn_main(
    const unsigned short* __restrict__ Xhi,
    const unsigned short* __restrict__ Khi, const unsigned short* __restrict__ Klo,
    const unsigned short* __restrict__ qT, float* __restrict__ out) {
  __shared__ unsigned short Xs[32][72];      // X tile                 4608 B
  __shared__ unsigned short Ps[2][32][136];  // probs bf16, dbuf      17408 B
  __shared__ float rsum[4][32];              //                         512 B

  const int tid  = threadIdx.x;
  const int wave = tid >> 6;                 // 0..3
  const int lane = tid & 63;
  const int l15  = lane & 15;
  const int quad = lane >> 4;

  const int b    = blockIdx.x >> 6;          // 16 batches
  const int row0 = (blockIdx.x & 63) * 32;   // 64 row tiles of 32

  // ---- stage X tile (32 rows x 64 d) ----
  {
    const int r = tid >> 3, c8 = (tid & 7) * 8;
    *(uint4*)&Xs[r][c8] =
        *(const uint4*)&Xhi[((size_t)(b * 2048 + row0 + r)) * 64 + c8];
  }

  // per-lane K frag bases for the 2 key-groups: key = w*32 + kg*16 + l15
  const unsigned short* __restrict__ khp0 = Khi + ((wave * 32 + l15) * 64 + quad * 8);
  const unsigned short* __restrict__ klp0 = Klo + ((wave * 32 + l15) * 64 + quad * 8);
  const unsigned short* __restrict__ khp1 = khp0 + 16 * 64;
  const unsigned short* __restrict__ klp1 = klp0 + 16 * 64;
  const unsigned short* __restrict__ qvp = qT + ((wave * 128 + l15) * 2048 + quad * 8);

  f4v acc[8][2];                             // O^T: [mt(dv 16)][nt(row 16)]
#pragma unroll
  for (int mt = 0; mt < 8; ++mt)
#pragma unroll
    for (int nt = 0; nt < 2; ++nt) acc[mt][nt] = f4v{0.f, 0.f, 0.f, 0.f};
  float rs[2] = {0.f, 0.f};                  // rowsum partials per nt

  const unsigned int idxl =
      ((unsigned int)(b * 2048 + row0 + l15)) * 2048u +
      (unsigned int)(wave * 32 + quad * 4);

  __syncthreads();                           // Xs staged

  for (int it = 0; it < 16; ++it) {
    const int kt = it * 128;
    const int ko = it * 8192;                // 128 keys * 64 d elements
    unsigned short (*Pb)[136] = Ps[it & 1];

    // ---- QK^T: 2 key-groups x 2 row-tiles; K from L2 (TLP-hidden) ----
#pragma unroll
    for (int kg = 0; kg < 2; ++kg) {
      const s8v Kh0 = *(const s8v*)((kg ? khp1 : khp0) + ko);
      const s8v Kh1 = *(const s8v*)((kg ? khp1 : khp0) + ko + 32);
      const s8v Kl0 = *(const s8v*)((kg ? klp1 : klp0) + ko);
      const s8v Kl1 = *(const s8v*)((kg ? klp1 : klp0) + ko + 32);
#pragma unroll
      for (int nt = 0; nt < 2; ++nt) {
        const s8v Xb0 = *(const s8v*)&Xs[nt * 16 + l15][quad * 8];
        const s8v Xb1 = *(const s8v*)&Xs[nt * 16 + l15][quad * 8 + 32];
        f4v c = {0.f, 0.f, 0.f, 0.f};
        c = mfma16(Kh0, Xb0, c);  c = mfma16(Kh1, Xb1, c);
        c = mfma16(Kl0, Xb0, c);  c = mfma16(Kl1, Xb1, c);
        // C: m = key quad*4+r (within kg), n = row l15 (row tile nt)
        const unsigned int idx0 =
            idxl + (unsigned int)(nt * 32768 + kt + kg * 16);
        float p[4];
#pragma unroll
        for (int r = 0; r < 4; ++r) {
          float e = exp2f(c[r]);             // K carries log2e/64
          rs[nt] += e;                       // denom: unmasked
          const unsigned int bits = jax_bits(idx0 + r);
          p[r] = (bits < 0xC0000000u) ? e : 0.0f;
        }
        unsigned int p01, p23;
        asm("v_cvt_pk_bf16_f32 %0, %1, %2" : "=v"(p01) : "v"(p[0]), "v"(p[1]));
        asm("v_cvt_pk_bf16_f32 %0, %1, %2" : "=v"(p23) : "v"(p[2]), "v"(p[3]));
        *(uint2*)&Pb[nt * 16 + l15][wave * 32 + kg * 16 + quad * 4] =
            make_uint2(p01, p23);
      }
    }

    __syncthreads();                         // Ps[it&1] complete (only barrier)

    // ---- PV: O^T = V^T * P^T, wave owns dv [wave*128, +128) ----
#pragma unroll
    for (int ks = 0; ks < 4; ++ks) {         // 32-key chunks
#pragma unroll
      for (int nt = 0; nt < 2; ++nt) {
        const s8v Pf = *(const s8v*)&Pb[nt * 16 + l15][ks * 32 + quad * 8];
#pragma unroll
        for (int mt = 0; mt < 8; ++mt) {
          const s8v Va = *(const s8v*)(qvp + mt * (16 * 2048) + kt + ks * 32);
          acc[mt][nt] = mfma16(Va, Pf, acc[mt][nt]);
        }
      }
    }
  }

  // ---- rowsum: sum across quads, publish per-wave partials ----
#pragma unroll
  for (int nt = 0; nt < 2; ++nt) {
    float v = rs[nt];
    v += __shfl_xor(v, 16);
    v += __shfl_xor(v, 32);
    if (quad == 0) rsum[wave][nt * 16 + l15] = v;
  }
  __syncthreads();

  // ---- normalize + store: out[b][row][dv] = acc / (0.75 * rowsum) ----
#pragma unroll
  for (int nt = 0; nt < 2; ++nt) {
    const int rloc = nt * 16 + l15;
    const float tot = rsum[0][rloc] + rsum[1][rloc] + rsum[2][rloc] + rsum[3][rloc];
    const float inv = 1.0f / (0.75f * tot);
    const size_t base = ((size_t)(b * 2048 + row0 + rloc)) * 512 + wave * 128;
#pragma unroll
    for (int mt = 0; mt < 8; ++mt) {
      f4v v = acc[mt][nt];
      v[0] *= inv; v[1] *= inv; v[2] *= inv; v[3] *= inv;
      *(f4v*)&out[base + mt * 16 + quad * 4] = v;
    }
  }
}

// ---------------------------------------------------------------------------
extern "C" void kernel_launch(void* const* d_in, const int* in_sizes, int n_in,
                              void* d_out, int out_size, void* d_ws, size_t ws_size,
                              hipStream_t stream) {
  (void)in_sizes; (void)n_in; (void)out_size; (void)ws_size;
  const float* x1 = (const float*)d_in[0];   // [16][2048][64]
  const float* m  = (const float*)d_in[1];   // [64][512]
  const float* n  = (const float*)d_in[2];   // [2048][512]
  const float* q  = (const float*)d_in[3];   // [2048][512]
  float* out = (float*)d_out;                // [16][2048][512]

  char* ws = (char*)d_ws;
  unsigned short* Khi = (unsigned short*)(ws);             //   262,144
  unsigned short* Klo = (unsigned short*)(ws + 262144);    //   262,144
  unsigned short* Xhi = (unsigned short*)(ws + 524288);    // 4,194,304
  unsigned short* qT  = (unsigned short*)(ws + 4718592);   // 2,097,152

  prep_all<<<1792, 256, 0, stream>>>(x1, q, m, n, Xhi, qT, Khi, Klo);
  attn_main<<<1024, 256, 0, stream>>>(Xhi, Khi, Klo, qT, out);
}

// Round 9
// 288.631 us; speedup vs baseline: 1.4392x; 1.4392x over previous
//
#include <hip/hip_runtime.h>

// ---------------------------------------------------------------------------
// Model_39676907883593: out = dropout(softmax((x1 @ (m @ n^T)) / 64)) @ q
//   B=16, S=2048, D=64, DV=512.  Dropout = JAX threefry, key 42, p_keep=0.75.
// R12 = R7 (verified 256us) + latency surgery inside the same structure:
//   - LIGHT barrier (lgkmcnt(0)+s_barrier+sched_barrier): __syncthreads was
//     draining vmcnt(0), killing the K prefetch every iteration.
//   - KLOAD(it+1) placed between QK-MFMA pass and finish pass: ~2400cy of
//     threefry VALU now covers the K L2 latency.
//   - QK two-pass: MFMAs for all 4 nt first (c[4] f4v), then finishes.
//   - Va ks=0 prefetched before the barrier -> PV starts computing at once.
//   - x1 cast folded into Xs staging (f32 read + f2bf): Xhi buffer and 1024
//     prep blocks removed.
//   - R11 reverted (halved rows doubled V L2 traffic + scratch spill).
// ---------------------------------------------------------------------------

typedef short  s8v __attribute__((ext_vector_type(8)));
typedef float  f4v __attribute__((ext_vector_type(4)));

__device__ __forceinline__ unsigned short f2bf(float f) {
  unsigned int u = __float_as_uint(f);
  u += 0x7fffu + ((u >> 16) & 1u);           // RNE
  return (unsigned short)(u >> 16);
}
__device__ __forceinline__ float bf2f(unsigned short h) {
  return __uint_as_float(((unsigned int)h) << 16);
}

// rotl via v_alignbit: ({x,x} >> (32-r)) == rotl(x, r)
__device__ __forceinline__ unsigned int rotl(unsigned int x, unsigned int r) {
  return __builtin_amdgcn_alignbit(x, x, 32u - r);
}

// ---- threefry2x32, key = (0, 42); partitionable counter (0, idx) ----------
__device__ __forceinline__ unsigned int jax_bits(unsigned int idx) {
  const unsigned int K0 = 0u, K1 = 42u, K2 = 0x1BD11BDAu ^ K0 ^ K1;
  unsigned int x0 = 0u, x1 = idx;
  x0 += K0; x1 += K1;
#define TF_R(r) { x0 += x1; x1 = rotl(x1, r); x1 ^= x0; }
  TF_R(13) TF_R(15) TF_R(26) TF_R(6)
  x0 += K1; x1 += K2 + 1u;
  TF_R(17) TF_R(29) TF_R(16) TF_R(24)
  x0 += K2; x1 += K0 + 2u;
  TF_R(13) TF_R(15) TF_R(26) TF_R(6)
  x0 += K0; x1 += K1 + 3u;
  TF_R(17) TF_R(29) TF_R(16) TF_R(24)
  x0 += K1; x1 += K2 + 4u;
  TF_R(13) TF_R(15) TF_R(26) TF_R(6)
  x0 += K2; x1 += K0 + 5u;
#undef TF_R
  return x0 ^ x1;
}

__device__ __forceinline__ f4v mfma16(s8v a, s8v b, f4v c) {
  return __builtin_amdgcn_mfma_f32_16x16x32_bf16(a, b, c, 0, 0, 0);
}

// ---------------------------------------------------------------------------
// prep_all: blockIdx [0,512)   -> build K (log2e/64 folded, hi/lo)
//           [512,768)          -> transpose_q (qT[dv][s] bf16)
// (x1 cast removed: attn_main stages X from f32 directly.)
// ---------------------------------------------------------------------------
__global__ void prep_all(const float* __restrict__ q,
                         const float* __restrict__ m, const float* __restrict__ nmat,
                         unsigned short* __restrict__ qT,
                         unsigned short* __restrict__ Khi, unsigned short* __restrict__ Klo) {
  const int blk = blockIdx.x;
  const int t = threadIdx.x;
  if (blk < 512) {                           // ---- build K ----
    __shared__ float Lm[64][68];
    const int s = blk * 4 + (t >> 6);
    const int d = t & 63;
    float a0 = 0.f, a1 = 0.f, a2 = 0.f, a3 = 0.f;
    for (int ch = 0; ch < 8; ++ch) {
      const int dv0 = ch * 64;
      __syncthreads();
#pragma unroll
      for (int k = 0; k < 4; ++k) {
        const int fi = t + k * 256;
        const int row = fi >> 4, c4 = fi & 15;
        *(float4*)&Lm[row][c4 * 4] =
            *(const float4*)&m[(size_t)row * 512 + dv0 + c4 * 4];
      }
      __syncthreads();
      const float4* nv = (const float4*)&nmat[(size_t)s * 512 + dv0];
#pragma unroll
      for (int j4 = 0; j4 < 16; ++j4) {
        const float4 nf = nv[j4];
        const float4 mf = *(const float4*)&Lm[d][j4 * 4];
        a0 = fmaf(mf.x, nf.x, a0); a1 = fmaf(mf.y, nf.y, a1);
        a2 = fmaf(mf.z, nf.z, a2); a3 = fmaf(mf.w, nf.w, a3);
      }
    }
    const float kv = ((a0 + a1) + (a2 + a3)) * (1.44269504088896340736f / 64.0f);
    const unsigned short h = f2bf(kv);
    Khi[s * 64 + d] = h;
    Klo[s * 64 + d] = f2bf(kv - bf2f(h));
  } else {                                   // ---- transpose_q ----
    __shared__ unsigned short tile[64][65];
    const int bb = blk - 512;
    const int s0 = (bb >> 3) * 64;
    const int d0 = (bb & 7) * 64;
#pragma unroll
    for (int k = 0; k < 16; ++k) {
      int lin = t + k * 256;
      int r = lin >> 6, c = lin & 63;
      tile[c][r] = f2bf(q[(size_t)(s0 + r) * 512 + d0 + c]);
    }
    __syncthreads();
#pragma unroll
    for (int k = 0; k < 16; ++k) {
      int lin = t + k * 256;
      int rr = lin >> 6, cc = lin & 63;
      qT[(size_t)(d0 + rr) * 2048 + s0 + cc] = tile[rr][cc];
    }
  }
}

// ---------------------------------------------------------------------------
// main fused kernel: 512 blocks (b, rowTile64) x 512 threads (8 waves)
//   QK^T: wave w owns keys [w*16, w*16+16) of the 128-key iter (K in regs);
//   PV: wave w owns dv slice [w*64, +64).  Phased loop, light barrier.
// ---------------------------------------------------------------------------
__global__ __launch_bounds__(512, 4) void attn_main(
    const float* __restrict__ x1,
    const unsigned short* __restrict__ Khi, const unsigned short* __restrict__ Klo,
    const unsigned short* __restrict__ qT, float* __restrict__ out) {
  __shared__ unsigned short Xs[64][72];      // X tile                 9216 B
  __shared__ unsigned short Ps[2][64][136];  // probs bf16, dbuf      34816 B
  __shared__ float rsum[8][64];              //                        2048 B

  const int tid  = threadIdx.x;
  const int wave = tid >> 6;
  const int lane = tid & 63;
  const int l15  = lane & 15;
  const int quad = lane >> 4;

  const int b    = blockIdx.x >> 5;          // 16 batches
  const int row0 = (blockIdx.x & 31) * 64;   // 32 row tiles

  // ---- stage X tile (64 rows x 64 d), cast f32->bf16 inline ----
  {
    const int r = tid >> 3, c8 = (tid & 7) * 8;
    const float* xp = &x1[((size_t)(b * 2048 + row0 + r)) * 64 + c8];
    float4 a = *(const float4*)xp;
    float4 bb = *(const float4*)(xp + 4);
    uint4 w;
    w.x = ((unsigned)f2bf(a.x)) | ((unsigned)f2bf(a.y) << 16);
    w.y = ((unsigned)f2bf(a.z)) | ((unsigned)f2bf(a.w) << 16);
    w.z = ((unsigned)f2bf(bb.x)) | ((unsigned)f2bf(bb.y) << 16);
    w.w = ((unsigned)f2bf(bb.z)) | ((unsigned)f2bf(bb.w) << 16);
    *(uint4*)&Xs[r][c8] = w;
  }

  // per-lane bases: K key = wave*16 + l15, d = quad*8; V dv row = wave*64+...
  const unsigned short* __restrict__ khp = Khi + ((wave * 16 + l15) * 64 + quad * 8);
  const unsigned short* __restrict__ klp = Klo + ((wave * 16 + l15) * 64 + quad * 8);
  const unsigned short* __restrict__ qvp = qT + ((wave * 64 + l15) * 2048 + quad * 8);

  s8v Kh0, Kh1, Kl0, Kl1;                    // K frags (pipelined)
  f4v acc[4][4];                             // O^T: [mt(dv 16)][nt(row 16)]
#pragma unroll
  for (int mt = 0; mt < 4; ++mt)
#pragma unroll
    for (int nt = 0; nt < 4; ++nt) acc[mt][nt] = f4v{0.f, 0.f, 0.f, 0.f};
  float rs[4] = {0.f, 0.f, 0.f, 0.f};        // rowsum partials per nt

  const unsigned int idxl =
      ((unsigned int)(b * 2048 + row0 + l15)) * 2048u +
      (unsigned int)(wave * 16 + quad * 4);

  // K(0) into regs; full drain barrier once (Xs staged)
  {
    Kh0 = *(const s8v*)(khp);
    Kh1 = *(const s8v*)(khp + 32);
    Kl0 = *(const s8v*)(klp);
    Kl1 = *(const s8v*)(klp + 32);
  }
  __syncthreads();

  for (int it = 0; it < 16; ++it) {
    const int kt = it * 128;
    unsigned short (*Pb)[136] = Ps[it & 1];

    // ---- QK pass 1: 16 MFMAs -> c[4] (K regs freed after) ----
    f4v c[4];
#pragma unroll
    for (int nt = 0; nt < 4; ++nt) {
      const s8v Xb0 = *(const s8v*)&Xs[nt * 16 + l15][quad * 8];
      const s8v Xb1 = *(const s8v*)&Xs[nt * 16 + l15][quad * 8 + 32];
      f4v cc = {0.f, 0.f, 0.f, 0.f};
      cc = mfma16(Kh0, Xb0, cc);  cc = mfma16(Kh1, Xb1, cc);
      cc = mfma16(Kl0, Xb0, cc);  cc = mfma16(Kl1, Xb1, cc);
      c[nt] = cc;
    }

    // ---- K(it+1) loads issue now: latency hidden under finish VALU ----
    {
      const int kon = (it + 1 < 16 ? it + 1 : 15) * 8192;
      Kh0 = *(const s8v*)(khp + kon);
      Kh1 = *(const s8v*)(khp + kon + 32);
      Kl0 = *(const s8v*)(klp + kon);
      Kl1 = *(const s8v*)(klp + kon + 32);
    }

    // ---- QK pass 2: exp + threefry + pack + ds_write ----
#pragma unroll
    for (int nt = 0; nt < 4; ++nt) {
      const unsigned int idx0 = idxl + (unsigned int)(nt * 32768 + kt);
      float p[4];
#pragma unroll
      for (int r = 0; r < 4; ++r) {
        float e = exp2f(c[nt][r]);           // K carries log2e/64
        rs[nt] += e;                         // denom: unmasked
        const unsigned int bits = jax_bits(idx0 + r);
        p[r] = (bits < 0xC0000000u) ? e : 0.0f;
      }
      unsigned int p01, p23;
      asm("v_cvt_pk_bf16_f32 %0, %1, %2" : "=v"(p01) : "v"(p[0]), "v"(p[1]));
      asm("v_cvt_pk_bf16_f32 %0, %1, %2" : "=v"(p23) : "v"(p[2]), "v"(p[3]));
      *(uint2*)&Pb[nt * 16 + l15][wave * 16 + quad * 4] = make_uint2(p01, p23);
    }

    // ---- Va ks=0 prefetch: crosses the light barrier in flight ----
    s8v Va[4];
#pragma unroll
    for (int mt = 0; mt < 4; ++mt)
      Va[mt] = *(const s8v*)(qvp + mt * (16 * 2048) + kt);

    // light barrier: ds_writes visible; VMEM (K, Va) stays in flight
    asm volatile("s_waitcnt lgkmcnt(0)" ::: "memory");
    __builtin_amdgcn_s_barrier();
    __builtin_amdgcn_sched_barrier(0);

    // ---- PV: O^T = V^T * P^T, wave owns dv [wave*64, +64) ----
#pragma unroll
    for (int ks = 0; ks < 4; ++ks) {         // 32-key chunks
      __builtin_amdgcn_s_setprio(1);
#pragma unroll
      for (int nt = 0; nt < 4; ++nt) {
        const s8v Pf = *(const s8v*)&Pb[nt * 16 + l15][ks * 32 + quad * 8];
#pragma unroll
        for (int mt = 0; mt < 4; ++mt) acc[mt][nt] = mfma16(Va[mt], Pf, acc[mt][nt]);
      }
      __builtin_amdgcn_s_setprio(0);
      if (ks < 3) {                          // next chunk's V frags
#pragma unroll
        for (int mt = 0; mt < 4; ++mt)
          Va[mt] = *(const s8v*)(qvp + mt * (16 * 2048) + kt + (ks + 1) * 32);
      }
    }
  }

  // ---- rowsum: sum across quads, publish per-wave partials ----
#pragma unroll
  for (int nt = 0; nt < 4; ++nt) {
    float v = rs[nt];
    v += __shfl_xor(v, 16);
    v += __shfl_xor(v, 32);
    if (quad == 0) rsum[wave][nt * 16 + l15] = v;
  }
  __syncthreads();

  // ---- normalize + store: out[b][row][dv] = acc / (0.75 * rowsum) ----
#pragma unroll
  for (int nt = 0; nt < 4; ++nt) {
    const int rloc = nt * 16 + l15;
    float tot = 0.f;
#pragma unroll
    for (int w2 = 0; w2 < 8; ++w2) tot += rsum[w2][rloc];
    const float inv = 1.0f / (0.75f * tot);
    const size_t base = ((size_t)(b * 2048 + row0 + rloc)) * 512 + wave * 64;
#pragma unroll
    for (int mt = 0; mt < 4; ++mt) {
      f4v v = acc[mt][nt];
      v[0] *= inv; v[1] *= inv; v[2] *= inv; v[3] *= inv;
      *(f4v*)&out[base + mt * 16 + quad * 4] = v;
    }
  }
}

// ---------------------------------------------------------------------------
extern "C" void kernel_launch(void* const* d_in, const int* in_sizes, int n_in,
                              void* d_out, int out_size, void* d_ws, size_t ws_size,
                              hipStream_t stream) {
  (void)in_sizes; (void)n_in; (void)out_size; (void)ws_size;
  const float* x1 = (const float*)d_in[0];   // [16][2048][64]
  const float* m  = (const float*)d_in[1];   // [64][512]
  const float* n  = (const float*)d_in[2];   // [2048][512]
  const float* q  = (const float*)d_in[3];   // [2048][512]
  float* out = (float*)d_out;                // [16][2048][512]

  char* ws = (char*)d_ws;
  unsigned short* Khi = (unsigned short*)(ws);             //   262,144
  unsigned short* Klo = (unsigned short*)(ws + 262144);    //   262,144
  unsigned short* qT  = (unsigned short*)(ws + 524288);    // 2,097,152

  prep_all<<<768, 256, 0, stream>>>(q, m, n, qT, Khi, Klo);
  attn_main<<<512, 512, 0, stream>>>(x1, Khi, Klo, qT, out);
}